// Round 2
// baseline (627.973 us; speedup 1.0000x reference)
//
#include <hip/hip_runtime.h>

// Capsule routing B=32 I=64 J=1152 K=32 M=16, routings=3, via MFMA.
// u_hat[k,b] for one (i,j) == one v_mfma_f32_32x32x16_bf16 (K=16=m).
// Split-bf16 (hi/lo) 3-MFMA per j keeps ~f32 accuracy.
// 5 W-sweeps (s0, a0, s1, a1, s2); W read coalesced straight from global.
// Side tensors kept in transposed layouts for lane-coalesced access:
//   c_t[i][j][b], o_t[i][k][b], br_t[i][j][b];  s[b][i][k] (atomic-reduced).

#define Ii 64
#define Jj 1152
#define Kk 32
#define Bb 32

typedef short  bf16x8 __attribute__((ext_vector_type(8)));
typedef float  f32x16 __attribute__((ext_vector_type(16)));
typedef float  f32x4  __attribute__((ext_vector_type(4)));

__device__ __forceinline__ void split2(float a, float b, unsigned &hi, unsigned &lo){
  unsigned ua = __float_as_uint(a), ub = __float_as_uint(b);
  unsigned ha = ua & 0xFFFF0000u, hb = ub & 0xFFFF0000u;
  hi = (ha >> 16) | hb;
  float la = a - __uint_as_float(ha);
  float lb = b - __uint_as_float(hb);
  lo = ((__float_as_uint(la) & 0xFFFF0000u) >> 16) | (__float_as_uint(lb) & 0xFFFF0000u);
}

__device__ __forceinline__ void split8(const float* v, bf16x8 &hi, bf16x8 &lo){
  union U { bf16x8 v; unsigned u[4]; } H, L;
#pragma unroll
  for (int p=0;p<4;p++) split2(v[2*p], v[2*p+1], H.u[p], L.u[p]);
  hi = H.v; lo = L.v;
}

// ---- s pass: s[b,i,k] += sum_j c[b,i,j] * u_hat[b,i,j,k]  (c folded into B)
template<int FIRST>
__global__ __launch_bounds__(256, 3)
void k_s(const float* __restrict__ Wp, const float* __restrict__ xp,
         const float* __restrict__ ct, float* __restrict__ sp)
{
  __shared__ float red[4*1088];
  const int t    = threadIdx.x;
  const int w    = t >> 6, lane = t & 63;
  const int kk   = lane & 31;        // A row (capsule k)
  const int h    = lane >> 5;        // k-group (m 0..7 / 8..15)
  const int b    = lane & 31;        // B col (batch)
  const int i    = blockIdx.y;
  const int j0   = blockIdx.x*32 + w*8;

  f32x16 acc0 = {}, acc1 = {};

#pragma unroll
  for (int jj=0; jj<8; ++jj){
    const int j = j0 + jj;
    const float* wv = Wp + ((i*Jj + j)*512 + kk*16 + h*8);
    float a8[8];
    *(f32x4*)(a8)   = *(const f32x4*)(wv);
    *(f32x4*)(a8+4) = *(const f32x4*)(wv+4);
    const float* xv = xp + ((b*Jj + j)*16 + h*8);
    float x8[8];
    *(f32x4*)(x8)   = *(const f32x4*)(xv);
    *(f32x4*)(x8+4) = *(const f32x4*)(xv+4);
    const float c = FIRST ? 0.015625f : ct[(i*Jj + j)*32 + b];
#pragma unroll
    for (int e=0;e<8;e++) x8[e] *= c;
    bf16x8 Ah, Al, Bh, Bl;
    split8(a8, Ah, Al);
    split8(x8, Bh, Bl);
    if (jj & 1){
      acc1 = __builtin_amdgcn_mfma_f32_32x32x16_bf16(Ah, Bh, acc1, 0,0,0);
      acc1 = __builtin_amdgcn_mfma_f32_32x32x16_bf16(Ah, Bl, acc1, 0,0,0);
      acc1 = __builtin_amdgcn_mfma_f32_32x32x16_bf16(Al, Bh, acc1, 0,0,0);
    } else {
      acc0 = __builtin_amdgcn_mfma_f32_32x32x16_bf16(Ah, Bh, acc0, 0,0,0);
      acc0 = __builtin_amdgcn_mfma_f32_32x32x16_bf16(Ah, Bl, acc0, 0,0,0);
      acc0 = __builtin_amdgcn_mfma_f32_32x32x16_bf16(Al, Bh, acc0, 0,0,0);
    }
  }

  f32x16 accs = acc0 + acc1;
  // cross-wave reduce (stride-17 rows: conflict-free scalar writes)
#pragma unroll
  for (int r=0;r<16;r++) red[w*1088 + lane*17 + r] = accs[r];
  __syncthreads();
#pragma unroll
  for (int q=0;q<4;q++){
    const int v  = t*4 + q;
    const int lv = v >> 4, r = v & 15;
    float sum = 0.f;
#pragma unroll
    for (int ww=0;ww<4;ww++) sum += red[ww*1088 + lv*17 + r];
    const int b2   = lv & 31, hh = lv >> 5;
    const int kcap = (r & 3) + 8*(r >> 2) + 4*hh;   // verified 32x32 D layout
    atomicAdd(&sp[(b2*Ii + i)*Kk + kcap], sum);
  }
}

// ---- agree pass: br_t[i][j][b] (+)= sum_k o[b,i,k]*u_hat[b,i,j,k]
template<int ADD>
__global__ __launch_bounds__(256, 3)
void k_ag(const float* __restrict__ Wp, const float* __restrict__ xp,
          const float* __restrict__ ot, float* __restrict__ brt)
{
  const int t    = threadIdx.x;
  const int w    = t >> 6, lane = t & 63;
  const int kk   = lane & 31;
  const int h    = lane >> 5;
  const int b    = lane & 31;
  const int i    = blockIdx.y;
  const int j0   = blockIdx.x*32 + w*8;

  float ov[16];
#pragma unroll
  for (int r=0;r<16;r++){
    const int kcap = (r & 3) + 8*(r >> 2) + 4*h;
    ov[r] = ot[(i*Kk + kcap)*Bb + b];
  }

#pragma unroll
  for (int jj=0; jj<8; ++jj){
    const int j = j0 + jj;
    const float* wv = Wp + ((i*Jj + j)*512 + kk*16 + h*8);
    float a8[8];
    *(f32x4*)(a8)   = *(const f32x4*)(wv);
    *(f32x4*)(a8+4) = *(const f32x4*)(wv+4);
    const float* xv = xp + ((b*Jj + j)*16 + h*8);
    float x8[8];
    *(f32x4*)(x8)   = *(const f32x4*)(xv);
    *(f32x4*)(x8+4) = *(const f32x4*)(xv+4);
    bf16x8 Ah, Al, Bh, Bl;
    split8(a8, Ah, Al);
    split8(x8, Bh, Bl);
    f32x16 d = {};
    d = __builtin_amdgcn_mfma_f32_32x32x16_bf16(Ah, Bh, d, 0,0,0);
    d = __builtin_amdgcn_mfma_f32_32x32x16_bf16(Ah, Bl, d, 0,0,0);
    d = __builtin_amdgcn_mfma_f32_32x32x16_bf16(Al, Bh, d, 0,0,0);
    float ap = 0.f;
#pragma unroll
    for (int r=0;r<16;r++) ap += ov[r]*d[r];
    ap += __shfl_xor(ap, 32);
    if (h == 0){
      const int idx = (i*Jj + j)*32 + b;
      const float prev = ADD ? brt[idx] : 0.f;
      brt[idx] = prev + ap;
    }
  }
}

// ---- softmax over i: c_t[i][j][b] = softmax_i(br_t[i][j][b]) --------------
__global__ __launch_bounds__(128, 4)
void k_soft(const float* __restrict__ brt, float* __restrict__ ct)
{
  const int t  = threadIdx.x;
  const int jl = t >> 5, b = t & 31;
  const int j  = blockIdx.x*4 + jl;
  float v[64];
  float mx = -1e30f;
#pragma unroll
  for (int ii=0; ii<64; ++ii){
    v[ii] = brt[(ii*Jj + j)*32 + b];
    mx = fmaxf(mx, v[ii]);
  }
  float sum = 0.f;
#pragma unroll
  for (int ii=0; ii<64; ++ii){ v[ii] = __expf(v[ii]-mx); sum += v[ii]; }
  const float inv = 1.f/sum;
#pragma unroll
  for (int ii=0; ii<64; ++ii)
    ct[(ii*Jj + j)*32 + b] = v[ii]*inv;
}

// ---- squash rows of 32; TR=1 -> o_t[i][k][b], TR=0 -> out[b][i][k] --------
template<int TR>
__global__ void k_squash(const float* __restrict__ sp, float* __restrict__ op)
{
  const int r = blockIdx.x*256 + threadIdx.x;
  if (r >= Bb*Ii) return;
  const float* row = sp + r*Kk;
  float q[32]; float s2 = 0.f;
#pragma unroll
  for (int u=0;u<32;u++){ q[u] = row[u]; s2 += q[u]*q[u]; }
  const float scale = s2/(1.f+s2) * rsqrtf(s2 + 1e-7f);
  if (TR){
    const int b = r >> 6, i = r & 63;
#pragma unroll
    for (int k=0;k<32;k++) op[(i*Kk + k)*Bb + b] = q[k]*scale;
  } else {
#pragma unroll
    for (int k=0;k<32;k++) op[r*Kk + k] = q[k]*scale;
  }
}

extern "C" void kernel_launch(void* const* d_in, const int* in_sizes, int n_in,
                              void* d_out, int out_size, void* d_ws, size_t ws_size,
                              hipStream_t stream)
{
  const float* x  = (const float*)d_in[0];   // [B,J,M]
  const float* Wp = (const float*)d_in[1];   // [I,J,K,M]
  float* out = (float*)d_out;                // [B,I,K]
  float* ws  = (float*)d_ws;
  // ws floats: s 65536 | o_t 65536 | br_t 2359296 | c_t 2359296 (~18.6MB)
  float* s  = ws;
  float* ot = ws + 65536;
  float* br = ws + 131072;
  float* ct = ws + 2490368;

  dim3 gs(36, 64), bs(256);
  dim3 gsm(288), bsm(128);

  // iter 0 (c uniform 1/64)
  hipMemsetAsync(s, 0, 65536*sizeof(float), stream);
  k_s<1><<<gs, bs, 0, stream>>>(Wp, x, nullptr, s);
  k_squash<1><<<dim3(8), dim3(256), 0, stream>>>(s, ot);
  k_ag<0><<<gs, bs, 0, stream>>>(Wp, x, ot, br);
  k_soft<<<gsm, bsm, 0, stream>>>(br, ct);

  // iter 1
  hipMemsetAsync(s, 0, 65536*sizeof(float), stream);
  k_s<0><<<gs, bs, 0, stream>>>(Wp, x, ct, s);
  k_squash<1><<<dim3(8), dim3(256), 0, stream>>>(s, ot);
  k_ag<1><<<gs, bs, 0, stream>>>(Wp, x, ot, br);
  k_soft<<<gsm, bsm, 0, stream>>>(br, ct);

  // iter 2
  hipMemsetAsync(s, 0, 65536*sizeof(float), stream);
  k_s<0><<<gs, bs, 0, stream>>>(Wp, x, ct, s);
  k_squash<0><<<dim3(8), dim3(256), 0, stream>>>(s, out);
}

// Round 3
// 187.650 us; speedup vs baseline: 3.3465x; 3.3465x over previous
//
#include <hip/hip_runtime.h>

// Capsule routing B=32 I=64 J=1152 K=32 M=16, routings=3, via MFMA.
// u_hat[k,b] per (i,j) = one v_mfma_f32_32x32x16_bf16; split-bf16 hi/lo
// 3-MFMA keeps ~f32 accuracy. 5 W sweeps; W read coalesced from global
// with explicit 8-j register preload. No atomics: k_s writes per-block
// partials, k_redsq reduces + squashes. Softmax stored as (max, 1/sum)
// per (j,b); k_s reconstructs c = exp(b-m)*invZ on the fly.
// ws (floats): spart 2359296 | br 2359296 | mz 73728 (ot aliases mz) ~19.2MB

#define Ii 64
#define Jj 1152
#define Kk 32
#define Bb 32
#define NJB 36

typedef short  bf16x8 __attribute__((ext_vector_type(8)));
typedef float  f32x16 __attribute__((ext_vector_type(16)));
typedef float  f32x4  __attribute__((ext_vector_type(4)));

__device__ __forceinline__ void split2(float a, float b, unsigned &hi, unsigned &lo){
  unsigned ua = __float_as_uint(a), ub = __float_as_uint(b);
  unsigned ha = ua & 0xFFFF0000u, hb = ub & 0xFFFF0000u;
  hi = (ha >> 16) | hb;
  float la = a - __uint_as_float(ha);
  float lb = b - __uint_as_float(hb);
  lo = ((__float_as_uint(la) & 0xFFFF0000u) >> 16) | (__float_as_uint(lb) & 0xFFFF0000u);
}

__device__ __forceinline__ void split8(const float* v, bf16x8 &hi, bf16x8 &lo){
  union U { bf16x8 v; unsigned u[4]; } H, L;
#pragma unroll
  for (int p=0;p<4;p++) split2(v[2*p], v[2*p+1], H.u[p], L.u[p]);
  hi = H.v; lo = L.v;
}

// ---- s pass: partial s over this block's 32 j's --------------------------
template<int FIRST>
__global__ __launch_bounds__(256, 2)
void k_s(const float* __restrict__ Wp, const float* __restrict__ xp,
         const float* __restrict__ brt, const float* __restrict__ mp,
         const float* __restrict__ zp, float* __restrict__ spart)
{
  __shared__ float red[4*1088];
  const int t    = threadIdx.x;
  const int w    = t >> 6, lane = t & 63;
  const int kk   = lane & 31;
  const int h    = lane >> 5;
  const int b    = lane & 31;
  const int i    = blockIdx.y;
  const int j0   = blockIdx.x*32 + w*8;

  float a8[8][8], x8[8][8], cw[8];
#pragma unroll
  for (int jj=0; jj<8; ++jj){
    const int j = j0 + jj;
    const float* wv = Wp + ((size_t)(i*Jj + j)*512 + kk*16 + h*8);
    *(f32x4*)(a8[jj])   = *(const f32x4*)(wv);
    *(f32x4*)(a8[jj]+4) = *(const f32x4*)(wv+4);
    const float* xv = xp + ((b*Jj + j)*16 + h*8);
    *(f32x4*)(x8[jj])   = *(const f32x4*)(xv);
    *(f32x4*)(x8[jj]+4) = *(const f32x4*)(xv+4);
    if (FIRST) cw[jj] = 0.015625f;
    else {
      const float bv = brt[(i*Jj + j)*32 + b];
      cw[jj] = __expf(bv - mp[j*32 + b]) * zp[j*32 + b];
    }
  }

  f32x16 acc0 = {}, acc1 = {};
#pragma unroll
  for (int jj=0; jj<8; ++jj){
    float xs[8];
#pragma unroll
    for (int e=0;e<8;e++) xs[e] = x8[jj][e] * cw[jj];
    bf16x8 Ah, Al, Bh, Bl;
    split8(a8[jj], Ah, Al);
    split8(xs,     Bh, Bl);
    if (jj & 1){
      acc1 = __builtin_amdgcn_mfma_f32_32x32x16_bf16(Ah, Bh, acc1, 0,0,0);
      acc1 = __builtin_amdgcn_mfma_f32_32x32x16_bf16(Ah, Bl, acc1, 0,0,0);
      acc1 = __builtin_amdgcn_mfma_f32_32x32x16_bf16(Al, Bh, acc1, 0,0,0);
    } else {
      acc0 = __builtin_amdgcn_mfma_f32_32x32x16_bf16(Ah, Bh, acc0, 0,0,0);
      acc0 = __builtin_amdgcn_mfma_f32_32x32x16_bf16(Ah, Bl, acc0, 0,0,0);
      acc0 = __builtin_amdgcn_mfma_f32_32x32x16_bf16(Al, Bh, acc0, 0,0,0);
    }
  }

  f32x16 accs = acc0 + acc1;
#pragma unroll
  for (int r=0;r<16;r++) red[w*1088 + lane*17 + r] = accs[r];
  __syncthreads();
  f32x4 outv;
#pragma unroll
  for (int q=0;q<4;q++){
    const int v  = t*4 + q;
    const int lv = v >> 4, r = v & 15;
    float sum = 0.f;
#pragma unroll
    for (int ww=0;ww<4;ww++) sum += red[ww*1088 + lv*17 + r];
    outv[q] = sum;
  }
  *(f32x4*)&spart[((size_t)blockIdx.x*Ii + i)*1024 + t*4] = outv;
}

// ---- reduce 36 partials + squash; TR=1 -> o_t[i][k][b], TR=0 -> out[b][i][k]
template<int TR>
__global__ __launch_bounds__(256)
void k_redsq(const float* __restrict__ spart, float* __restrict__ outp)
{
  const int i = blockIdx.x, t = threadIdx.x;
  f32x4 a = {0.f,0.f,0.f,0.f};
#pragma unroll
  for (int jb=0;jb<NJB;jb++)
    a += *(const f32x4*)&spart[((size_t)jb*Ii + i)*1024 + t*4];

  const int b2 = (t>>2)&31, hh = t>>7, t3 = t&3;
  float ss = a.x*a.x + a.y*a.y + a.z*a.z + a.w*a.w;
  ss += __shfl_xor(ss,1);
  ss += __shfl_xor(ss,2);
  __shared__ float sp2[2][32];
  if (t3 == 0) sp2[hh][b2] = ss;
  __syncthreads();
  const float s2 = sp2[0][b2] + sp2[1][b2];
  const float scale = s2/(1.f+s2) * rsqrtf(s2 + 1e-7f);
#pragma unroll
  for (int q=0;q<4;q++){
    const int kcap = q + 8*t3 + 4*hh;
    const float val = a[q]*scale;
    if (TR) outp[(i*Kk + kcap)*Bb + b2] = val;
    else    outp[((size_t)b2*Ii + i)*Kk + kcap] = val;
  }
}

// ---- agree pass: br_t[i][j][b] (+)= sum_k o[b,i,k]*u_hat[b,i,j,k] --------
template<int ADD>
__global__ __launch_bounds__(256, 2)
void k_ag(const float* __restrict__ Wp, const float* __restrict__ xp,
          const float* __restrict__ ot, float* __restrict__ brt)
{
  const int t    = threadIdx.x;
  const int w    = t >> 6, lane = t & 63;
  const int kk   = lane & 31;
  const int h    = lane >> 5;
  const int b    = lane & 31;
  const int i    = blockIdx.y;
  const int j0   = blockIdx.x*32 + w*8;

  float ov[16];
#pragma unroll
  for (int r=0;r<16;r++){
    const int kcap = (r & 3) + 8*(r >> 2) + 4*h;
    ov[r] = ot[(i*Kk + kcap)*Bb + b];
  }

  float a8[8][8], x8[8][8], pv[8];
#pragma unroll
  for (int jj=0; jj<8; ++jj){
    const int j = j0 + jj;
    const float* wv = Wp + ((size_t)(i*Jj + j)*512 + kk*16 + h*8);
    *(f32x4*)(a8[jj])   = *(const f32x4*)(wv);
    *(f32x4*)(a8[jj]+4) = *(const f32x4*)(wv+4);
    const float* xv = xp + ((b*Jj + j)*16 + h*8);
    *(f32x4*)(x8[jj])   = *(const f32x4*)(xv);
    *(f32x4*)(x8[jj]+4) = *(const f32x4*)(xv+4);
    pv[jj] = ADD ? brt[(i*Jj + j)*32 + b] : 0.f;
  }

#pragma unroll
  for (int jj=0; jj<8; ++jj){
    bf16x8 Ah, Al, Bh, Bl;
    split8(a8[jj], Ah, Al);
    split8(x8[jj], Bh, Bl);
    f32x16 d = {};
    d = __builtin_amdgcn_mfma_f32_32x32x16_bf16(Ah, Bh, d, 0,0,0);
    d = __builtin_amdgcn_mfma_f32_32x32x16_bf16(Ah, Bl, d, 0,0,0);
    d = __builtin_amdgcn_mfma_f32_32x32x16_bf16(Al, Bh, d, 0,0,0);
    float ap = 0.f;
#pragma unroll
    for (int r=0;r<16;r++) ap += ov[r]*d[r];
    ap += __shfl_xor(ap, 32);
    if (h == 0)
      brt[(i*Jj + (j0+jj))*32 + b] = pv[jj] + ap;
  }
}

// ---- per-(j,b) softmax stats over i: m = max_i b, z = 1/sum exp(b-m) -----
__global__ __launch_bounds__(256)
void k_norm(const float* __restrict__ brt, float* __restrict__ mp,
            float* __restrict__ zp)
{
  const int t  = threadIdx.x;
  const int jl = t >> 5, b = t & 31;
  const int j  = blockIdx.x*8 + jl;
  float v[64];
  float mx = -1e30f;
#pragma unroll
  for (int ii=0; ii<64; ++ii){
    v[ii] = brt[(ii*Jj + j)*32 + b];
    mx = fmaxf(mx, v[ii]);
  }
  float sum = 0.f;
#pragma unroll
  for (int ii=0; ii<64; ++ii) sum += __expf(v[ii]-mx);
  mp[j*32 + b] = mx;
  zp[j*32 + b] = 1.f/sum;
}

extern "C" void kernel_launch(void* const* d_in, const int* in_sizes, int n_in,
                              void* d_out, int out_size, void* d_ws, size_t ws_size,
                              hipStream_t stream)
{
  const float* x  = (const float*)d_in[0];   // [B,J,M]
  const float* Wp = (const float*)d_in[1];   // [I,J,K,M]
  float* out = (float*)d_out;                // [B,I,K]
  float* ws  = (float*)d_ws;
  float* spart = ws;                         // 2359296 floats
  float* br    = ws + 2359296;               // 2359296 floats
  float* m     = ws + 4718592;               // 36864 floats
  float* z     = ws + 4755456;               // 36864 floats
  float* ot    = ws + 4718592;               // aliases m/z (disjoint lifetime)

  dim3 gs(NJB, Ii), bs(256);

  // iter 0 (c uniform 1/64)
  k_s<1><<<gs, bs, 0, stream>>>(Wp, x, nullptr, nullptr, nullptr, spart);
  k_redsq<1><<<dim3(64), bs, 0, stream>>>(spart, ot);
  k_ag<0><<<gs, bs, 0, stream>>>(Wp, x, ot, br);
  k_norm<<<dim3(144), bs, 0, stream>>>(br, m, z);

  // iter 1
  k_s<0><<<gs, bs, 0, stream>>>(Wp, x, br, m, z, spart);
  k_redsq<1><<<dim3(64), bs, 0, stream>>>(spart, ot);
  k_ag<1><<<gs, bs, 0, stream>>>(Wp, x, ot, br);
  k_norm<<<dim3(144), bs, 0, stream>>>(br, m, z);

  // iter 2
  k_s<0><<<gs, bs, 0, stream>>>(Wp, x, br, m, z, spart);
  k_redsq<0><<<dim3(64), bs, 0, stream>>>(spart, out);
}